// Round 6
// baseline (216.350 us; speedup 1.0000x reference)
//
#include <hip/hip_runtime.h>

#define D 32

typedef float fx4 __attribute__((ext_vector_type(4)));

// ---- Kernel 0: fp32 X -> packed bf16 (RNE) into workspace -----------------
__global__ __launch_bounds__(256)
void cvt_bf16(const float* __restrict__ X, uint* __restrict__ Xb, int total8) {
    int i = blockIdx.x * blockDim.x + threadIdx.x;
    if (i >= total8) return;
    const float4* src = (const float4*)X;
    float4 a = src[2 * i], b = src[2 * i + 1];
    auto pack2 = [](float lo, float hi) -> uint {
        uint ul = __float_as_uint(lo), uh = __float_as_uint(hi);
        ul = (ul + 0x7FFFu + ((ul >> 16) & 1u)) >> 16;
        uh = (uh + 0x7FFFu + ((uh >> 16) & 1u)) & 0xFFFF0000u;
        return ul | uh;
    };
    uint4 o;
    o.x = pack2(a.x, a.y); o.y = pack2(a.z, a.w);
    o.z = pack2(b.x, b.y); o.w = pack2(b.z, b.w);
    ((uint4*)Xb)[i] = o;
}

// ---- Pass kernel: gather-accumulate edges with ci in [lo, hi) -------------
// FINAL=false: write fp32 partial X_prime into out.
// FINAL=true : add partial from out, apply W, write final out.
template <bool FINAL>
__global__ __launch_bounds__(256, 4)
void gin_pass(const uint* __restrict__ Xb,   // N rows x 16 uints (32 bf16)
              const float* __restrict__ W,
              const int* __restrict__ rp,
              const int* __restrict__ ci,
              float* __restrict__ out,
              int n, int lo, int hi) {
    __shared__ float Wl[D * D];
    int tid = threadIdx.x;
    if (FINAL) {
        ((float4*)Wl)[tid] = ((const float4*)W)[tid];
        __syncthreads();
    }

    int wave = tid >> 6;
    int lane = tid & 63;
    int row = blockIdx.x * 4 + wave;
    if (row >= n) return;

    int start = rp[row];
    int deg   = rp[row + 1] - start;

    int g = lane >> 2;   // 16 edge groups per wave
    int s = lane & 3;    // uint4 slot: bf16 elements 8s .. 8s+7

    float acc[8] = {0.f, 0.f, 0.f, 0.f, 0.f, 0.f, 0.f, 0.f};

    for (int cb = 0; cb < deg; cb += 64) {
        int rem = deg - cb;
        int li = cb + lane;
        li = (li < deg) ? li : (deg - 1);
        // streamed once per pass: nontemporal so it doesn't evict the X slice
        int myci = __builtin_nontemporal_load(ci + start + li);

        #pragma unroll
        for (int it = 0; it < 4; ++it) {
            if (it * 16 < rem) {                  // wave-uniform skip
                int l = it * 16 + g;
                int c = __shfl(myci, (l < rem) ? l : 0, 64);
                bool valid = (l < rem) && (c >= lo) && (c < hi);
                if (valid) {                      // inactive lanes: no request
                    uint4 x = ((const uint4*)Xb)[(size_t)c * 4 + s];
                    uint q[4] = {x.x, x.y, x.z, x.w};
                    #pragma unroll
                    for (int k = 0; k < 4; ++k) {
                        acc[2 * k]     += __uint_as_float(q[k] << 16);
                        acc[2 * k + 1] += __uint_as_float(q[k] & 0xFFFF0000u);
                    }
                }
            }
        }
    }

    // Combine the 16 edge groups: xor-reduce over g bits (4, 8, 16, 32)
    #pragma unroll
    for (int off = 4; off < 64; off <<= 1) {
        #pragma unroll
        for (int k = 0; k < 8; ++k)
            acc[k] += __shfl_xor(acc[k], off, 64);
    }
    // lanes 0..3 (s) hold this slice's partial X_prime[row][8s .. 8s+7]

    if (!FINAL) {
        if (lane < 4) {
            fx4 a0 = {acc[0], acc[1], acc[2], acc[3]};
            fx4 a1 = {acc[4], acc[5], acc[6], acc[7]};
            fx4* dst = (fx4*)(out + (size_t)row * D);
            __builtin_nontemporal_store(a0, dst + 2 * s);
            __builtin_nontemporal_store(a1, dst + 2 * s + 1);
        }
    } else {
        if (lane < 4) {
            const fx4* src = (const fx4*)(out + (size_t)row * D);
            fx4 p0 = __builtin_nontemporal_load(src + 2 * s);
            fx4 p1 = __builtin_nontemporal_load(src + 2 * s + 1);
            acc[0] += p0.x; acc[1] += p0.y; acc[2] += p0.z; acc[3] += p0.w;
            acc[4] += p1.x; acc[5] += p1.y; acc[6] += p1.z; acc[7] += p1.w;
        }
        int j = lane & 31;
        float o = 0.f;
        #pragma unroll
        for (int ss = 0; ss < 4; ++ss) {
            #pragma unroll
            for (int k = 0; k < 8; ++k) {
                float a = __shfl(acc[k], ss, 64);
                o = fmaf(a, Wl[(8 * ss + k) * D + j], o);
            }
        }
        if (lane < 32) out[(size_t)row * D + j] = o;
    }
}

// ---- Fallback (fp32 gather, R2 structure) if ws too small -----------------
__global__ __launch_bounds__(256, 4)
void gin_fused_f32(const float* __restrict__ X,
                   const float* __restrict__ W,
                   const int* __restrict__ rp,
                   const int* __restrict__ ci,
                   float* __restrict__ out,
                   int n) {
    __shared__ float Wl[D * D];
    int tid = threadIdx.x;
    ((float4*)Wl)[tid] = ((const float4*)W)[tid];
    __syncthreads();

    int wave = tid >> 6, lane = tid & 63;
    int row = blockIdx.x * 4 + wave;
    if (row >= n) return;
    int start = rp[row];
    int deg   = rp[row + 1] - start;
    int g = lane >> 3, s = lane & 7;
    float4 acc = make_float4(0.f, 0.f, 0.f, 0.f);

    for (int cb = 0; cb < deg; cb += 64) {
        int rem = deg - cb;
        int li = cb + lane;
        li = (li < deg) ? li : (deg - 1);
        int myci = ci[start + li];
        float4 x[8]; float m[8];
        #pragma unroll
        for (int it = 0; it < 8; ++it) {
            if (it * 8 < rem) {
                int l  = it * 8 + g;
                int lc = (l < rem) ? l : (rem - 1);
                int c  = __shfl(myci, lc, 64);
                m[it]  = (l < rem) ? 1.f : 0.f;
                x[it]  = ((const float4*)(X + (size_t)c * D))[s];
            }
        }
        #pragma unroll
        for (int it = 0; it < 8; ++it) {
            if (it * 8 < rem) {
                acc.x = fmaf(m[it], x[it].x, acc.x);
                acc.y = fmaf(m[it], x[it].y, acc.y);
                acc.z = fmaf(m[it], x[it].z, acc.z);
                acc.w = fmaf(m[it], x[it].w, acc.w);
            }
        }
    }
    #pragma unroll
    for (int off = 8; off < 64; off <<= 1) {
        acc.x += __shfl_xor(acc.x, off, 64);
        acc.y += __shfl_xor(acc.y, off, 64);
        acc.z += __shfl_xor(acc.z, off, 64);
        acc.w += __shfl_xor(acc.w, off, 64);
    }
    int j = lane & 31;
    float o = 0.f;
    #pragma unroll
    for (int sg = 0; sg < 8; ++sg) {
        float ax = __shfl(acc.x, sg, 64);
        float ay = __shfl(acc.y, sg, 64);
        float az = __shfl(acc.z, sg, 64);
        float aw = __shfl(acc.w, sg, 64);
        int d = 4 * sg;
        o = fmaf(ax, Wl[(d    ) * D + j], o);
        o = fmaf(ay, Wl[(d + 1) * D + j], o);
        o = fmaf(az, Wl[(d + 2) * D + j], o);
        o = fmaf(aw, Wl[(d + 3) * D + j], o);
    }
    if (lane < 32) out[(size_t)row * D + j] = o;
}

extern "C" void kernel_launch(void* const* d_in, const int* in_sizes, int n_in,
                              void* d_out, int out_size, void* d_ws, size_t ws_size,
                              hipStream_t stream) {
    const float* X  = (const float*)d_in[0];
    const float* W  = (const float*)d_in[1];
    const int*   rp = (const int*)d_in[2];
    const int*   ci = (const int*)d_in[3];
    float* out = (float*)d_out;

    int n = in_sizes[2] - 1;                 // N nodes
    int nelem = in_sizes[0];                 // N * 32 floats
    size_t need = (size_t)nelem * 2;         // bf16 bytes
    int blocks = (n + 3) / 4;

    if (ws_size >= need) {
        uint* Xb = (uint*)d_ws;
        int total8 = nelem / 8;
        hipLaunchKernelGGL(cvt_bf16, dim3((total8 + 255) / 256), dim3(256), 0,
                           stream, X, Xb, total8);
        int mid = n / 2;   // 3.2 MB bf16 slice fits a 4 MB per-XCD L2
        hipLaunchKernelGGL((gin_pass<false>), dim3(blocks), dim3(256), 0, stream,
                           Xb, W, rp, ci, out, n, 0, mid);
        hipLaunchKernelGGL((gin_pass<true>), dim3(blocks), dim3(256), 0, stream,
                           Xb, W, rp, ci, out, n, mid, n);
    } else {
        hipLaunchKernelGGL(gin_fused_f32, dim3(blocks), dim3(256), 0, stream,
                           X, W, rp, ci, out, n);
    }
}

// Round 7
// 169.262 us; speedup vs baseline: 1.2782x; 1.2782x over previous
//
#include <hip/hip_runtime.h>

#define D 32

__global__ __launch_bounds__(256, 4)
void gin_fused2(const float* __restrict__ X,
                const float* __restrict__ W,
                const int* __restrict__ rp,
                const int* __restrict__ ci,
                float* __restrict__ out,
                int n) {
    __shared__ float Wl[D * D];
    int tid = threadIdx.x;
    ((float4*)Wl)[tid] = ((const float4*)W)[tid];
    __syncthreads();

    int wave = tid >> 6, lane = tid & 63;
    int r0 = (blockIdx.x * 4 + wave) * 2;     // this wave owns rows r0, r0+1
    if (r0 >= n) return;
    bool haveB = (r0 + 1 < n);

    // one coalesced load serves both rows' CSR offsets
    int nrp = haveB ? 3 : 2;
    int rv = (lane < nrp) ? rp[r0 + lane] : 0;
    int e0 = __shfl(rv, 0, 64);
    int e1 = __shfl(rv, 1, 64);
    int e2 = haveB ? __shfl(rv, 2, 64) : e1;

    int startA = e0, degA = e1 - e0;
    int startB = e1, degB = e2 - e1;

    int g = lane >> 3;          // edge sub-group 0..7
    int s = lane & 7;           // float4 slot 0..7 (32 floats = one row)

    float4 accA = make_float4(0.f, 0.f, 0.f, 0.f);
    float4 accB = make_float4(0.f, 0.f, 0.f, 0.f);

    int degM = degA > degB ? degA : degB;
    for (int cb = 0; cb < degM; cb += 64) {
        int remA = degA - cb, remB = degB - cb;

        // both index loads issue before either is consumed
        int ciA = 0, ciB = 0;
        if (remA > 0) {
            int li = cb + lane; li = li < degA ? li : degA - 1;
            ciA = ci[startA + li];
        }
        if (remB > 0) {
            int li = cb + lane; li = li < degB ? li : degB - 1;
            ciB = ci[startB + li];
        }

        float4 xA[8], xB[8];
        // phase 1: issue ALL gathers (up to 16) before any accumulation
        #pragma unroll
        for (int it = 0; it < 8; ++it) {
            if (it * 8 < remA) {                       // wave-uniform
                int l = it * 8 + g;
                int c = __shfl(ciA, l < remA ? l : remA - 1, 64);
                xA[it] = ((const float4*)(X + (size_t)c * D))[s];
            }
        }
        #pragma unroll
        for (int it = 0; it < 8; ++it) {
            if (it * 8 < remB) {
                int l = it * 8 + g;
                int c = __shfl(ciB, l < remB ? l : remB - 1, 64);
                xB[it] = ((const float4*)(X + (size_t)c * D))[s];
            }
        }
        // phase 2: masked accumulation (waitcnts batch here)
        #pragma unroll
        for (int it = 0; it < 8; ++it) {
            if (it * 8 < remA) {
                float m = (it * 8 + g < remA) ? 1.f : 0.f;
                accA.x = fmaf(m, xA[it].x, accA.x);
                accA.y = fmaf(m, xA[it].y, accA.y);
                accA.z = fmaf(m, xA[it].z, accA.z);
                accA.w = fmaf(m, xA[it].w, accA.w);
            }
        }
        #pragma unroll
        for (int it = 0; it < 8; ++it) {
            if (it * 8 < remB) {
                float m = (it * 8 + g < remB) ? 1.f : 0.f;
                accB.x = fmaf(m, xB[it].x, accB.x);
                accB.y = fmaf(m, xB[it].y, accB.y);
                accB.z = fmaf(m, xB[it].z, accB.z);
                accB.w = fmaf(m, xB[it].w, accB.w);
            }
        }
    }

    // reduce across edge groups (xor over g bits: 8, 16, 32)
    #pragma unroll
    for (int off = 8; off < 64; off <<= 1) {
        accA.x += __shfl_xor(accA.x, off, 64);
        accA.y += __shfl_xor(accA.y, off, 64);
        accA.z += __shfl_xor(accA.z, off, 64);
        accA.w += __shfl_xor(accA.w, off, 64);
        accB.x += __shfl_xor(accB.x, off, 64);
        accB.y += __shfl_xor(accB.y, off, 64);
        accB.z += __shfl_xor(accB.z, off, 64);
        accB.w += __shfl_xor(accB.w, off, 64);
    }
    // lanes with slot s hold aggregated X_prime[row][4s .. 4s+3] for both rows

    int j = lane & 31;
    float oA = 0.f, oB = 0.f;
    #pragma unroll
    for (int sg = 0; sg < 8; ++sg) {
        int d = 4 * sg;
        float a;
        a = __shfl(accA.x, sg, 64); oA = fmaf(a, Wl[(d    ) * D + j], oA);
        a = __shfl(accA.y, sg, 64); oA = fmaf(a, Wl[(d + 1) * D + j], oA);
        a = __shfl(accA.z, sg, 64); oA = fmaf(a, Wl[(d + 2) * D + j], oA);
        a = __shfl(accA.w, sg, 64); oA = fmaf(a, Wl[(d + 3) * D + j], oA);
        a = __shfl(accB.x, sg, 64); oB = fmaf(a, Wl[(d    ) * D + j], oB);
        a = __shfl(accB.y, sg, 64); oB = fmaf(a, Wl[(d + 1) * D + j], oB);
        a = __shfl(accB.z, sg, 64); oB = fmaf(a, Wl[(d + 2) * D + j], oB);
        a = __shfl(accB.w, sg, 64); oB = fmaf(a, Wl[(d + 3) * D + j], oB);
    }
    if (lane < 32) {
        out[(size_t)r0 * D + j] = oA;
    } else if (haveB) {
        out[(size_t)(r0 + 1) * D + j] = oB;
    }
}

extern "C" void kernel_launch(void* const* d_in, const int* in_sizes, int n_in,
                              void* d_out, int out_size, void* d_ws, size_t ws_size,
                              hipStream_t stream) {
    const float* X  = (const float*)d_in[0];
    const float* W  = (const float*)d_in[1];
    const int*   rp = (const int*)d_in[2];
    const int*   ci = (const int*)d_in[3];
    float* out = (float*)d_out;

    int n = in_sizes[2] - 1;                 // N nodes
    int pairs = (n + 1) / 2;                 // 2 rows per wave
    int blocks = (pairs + 3) / 4;            // 4 waves per block
    hipLaunchKernelGGL(gin_fused2, dim3(blocks), dim3(256), 0, stream,
                       X, W, rp, ci, out, n);
}